// Round 3
// baseline (536.135 us; speedup 1.0000x reference)
//
#include <hip/hip_runtime.h>
#include <hip/hip_bf16.h>

// Flow1: RealNVP coupling flow. K=32 B=4096 ZS=128 ZH=64 HS=50 NF=2.
// Round 3: fix ZPROC macro shadowing (local `float e` captured its own
// initializer `e.y` -> compile error). Macro locals now underscore-prefixed.
// Dtype-agnostic: detect bf16 vs fp32 from `mean` bit patterns per wave.
// Compute fp32; weights via fp32 (+transposed W1/W2) workspace.

typedef unsigned short ushort_t;
typedef unsigned int   uint_t;

#define KK   32
#define BB   4096
#define ZSD  128
#define ZHD  64
#define HSD  50
#define NFD  2
#define NROWS (KK*BB)

// fp32 weight workspace layout (floats)
#define OFF_W0  0                        // [4][HS][ZH]
#define OFF_B0  (OFF_W0 + 4*HSD*ZHD)     // [4][HS]
#define OFF_W1T (OFF_B0 + 4*HSD)         // [4][HS][ZH]  W1t[step][k][j] = W1[step][j][k]
#define OFF_B1  (OFF_W1T + 4*HSD*ZHD)    // [4][ZH]
#define OFF_W2T (OFF_B1 + 4*ZHD)         // [4][HS][ZH]
#define OFF_B2  (OFF_W2T + 4*HSD*ZHD)    // [4][ZH]
#define WS_FLOATS (OFF_B2 + 4*ZHD)       // 39112 floats = 156448 B

__device__ __forceinline__ float bflo(uint_t u){ union{uint_t i; float f;} v; v.i = u<<16; return v.f; }
__device__ __forceinline__ float bfhi(uint_t u){ union{uint_t i; float f;} v; v.i = u & 0xffff0000u; return v.f; }
__device__ __forceinline__ float bf2f(ushort_t u){ union{uint_t i; float f;} v; v.i = ((uint_t)u)<<16; return v.f; }
__device__ __forceinline__ ushort_t f2bf(float f){
  union{float f; uint_t i;} v; v.f = f;
  uint_t x = v.i;
  uint_t r = (x + 0x7fffu + ((x>>16)&1u)) >> 16;   // RNE
  return (ushort_t)r;
}

// 1 = buffers are bf16, 0 = buffers are fp32. Wave-uniform.
// bf16 N(0,1) data: low halfword's exponent field always in [64,192).
// fp32 data: those bits are mantissa bits (~uniform) -> ~32/64 hits.
__device__ __forceinline__ int detect_bf16(const uint_t* mw){
  uint_t w = mw[threadIdx.x & 63];
  uint_t elow = (w >> 7) & 0xffu;
  unsigned long long m = __ballot(elow >= 64u && elow < 192u);
  return (__popcll(m) >= 56) ? 1 : 0;
}

__device__ __forceinline__ float tanh_fast(float x){
  float ax = fabsf(x);
  float t  = __expf(-2.0f*ax);                  // (0,1], never overflows
  float r  = (1.0f - t) / (1.0f + t);           // >= 0
  union{float f; uint_t i;} u, s; u.f = r; s.f = x;
  u.i |= (s.i & 0x80000000u);                   // copy sign
  return u.f;
}

// sig = sigmoid(x), lsig = log(sigmoid(x)), stable for any finite x
__device__ __forceinline__ void sigmoid_log(float x, float& sig, float& lsig){
  float ax  = fabsf(x);
  float e   = __expf(-ax);                      // (0,1]
  float d   = 1.0f + e;
  float inv = 1.0f / d;                         // sigmoid(|x|)
  float ld  = __logf(d);                        // log(1+e) in [0, log2]
  bool pos  = (x >= 0.0f);
  sig  = pos ? inv : e*inv;
  lsig = pos ? -ld : x - ld;
}

__device__ __forceinline__ float wload(const void* p, int idx, int flag){
  return flag ? bf2f(((const ushort_t*)p)[idx]) : ((const float*)p)[idx];
}

__global__ void convert_weights(const void* __restrict__ W0,
                                const void* __restrict__ b0,
                                const void* __restrict__ W1,
                                const void* __restrict__ b1,
                                const void* __restrict__ W2,
                                const void* __restrict__ b2,
                                const void* __restrict__ mean,
                                float* __restrict__ ws)
{
  const int flag = detect_bf16((const uint_t*)mean);
  int t = blockIdx.x*256 + threadIdx.x;
  if (t < 4*HSD*ZHD){
    ws[OFF_W0 + t] = wload(W0, t, flag);
    int j = t % ZHD; int k = (t / ZHD) % HSD; int step = t/(ZHD*HSD);
    int src = (step*ZHD + j)*HSD + k;           // transpose W1/W2 per step
    ws[OFF_W1T + t] = wload(W1, src, flag);
    ws[OFF_W2T + t] = wload(W2, src, flag);
  }
  if (t < 4*HSD) ws[OFF_B0 + t] = wload(b0, t, flag);
  if (t < 4*ZHD){ ws[OFF_B1 + t] = wload(b1, t, flag); ws[OFF_B2 + t] = wload(b2, t, flag); }
}

template<bool WS>
__device__ __forceinline__ void coupling_step(
    int step,
    const float (&zin)[ZHD], float (&zout)[ZHD], float& logdet,
    const float* __restrict__ wf,
    const void* __restrict__ W0, const void* __restrict__ b0,
    const void* __restrict__ W1, const void* __restrict__ b1,
    const void* __restrict__ W2, const void* __restrict__ b2,
    float* __restrict__ hbuf, int tid)
{
  // ---- phase 1: h[k] = tanh(b0[k] + sum_j zin[j]*W0[k][j]) -> LDS ----
  #pragma unroll 2
  for (int k=0;k<HSD;++k){
    float a0=0.f,a1=0.f,a2=0.f,a3=0.f;
    if constexpr (WS){
      const float* w = wf + OFF_W0 + (step*HSD + k)*ZHD;
      #pragma unroll
      for (int j=0;j<ZHD;j+=4){
        a0 = fmaf(zin[j+0], w[j+0], a0);
        a1 = fmaf(zin[j+1], w[j+1], a1);
        a2 = fmaf(zin[j+2], w[j+2], a2);
        a3 = fmaf(zin[j+3], w[j+3], a3);
      }
    } else {
      const ushort_t* w = (const ushort_t*)W0 + (step*HSD + k)*ZHD;
      #pragma unroll
      for (int j=0;j<ZHD;j+=4){
        a0 = fmaf(zin[j+0], bf2f(w[j+0]), a0);
        a1 = fmaf(zin[j+1], bf2f(w[j+1]), a1);
        a2 = fmaf(zin[j+2], bf2f(w[j+2]), a2);
        a3 = fmaf(zin[j+3], bf2f(w[j+3]), a3);
      }
    }
    float bias = WS ? wf[OFF_B0 + step*HSD + k] : bf2f(((const ushort_t*)b0)[step*HSD + k]);
    float x = ((a0+a1)+(a2+a3)) + bias;
    hbuf[k*256 + tid] = tanh_fast(x);           // private column: no barrier
  }
  // ---- phase 2: mew/sig -> update zout, logdet ----
  #pragma unroll
  for (int q=0;q<4;++q){
    float am[16], as_[16];
    #pragma unroll
    for (int jj=0;jj<16;++jj){
      int j = q*16 + jj;
      am[jj]  = WS ? wf[OFF_B1 + step*ZHD + j] : bf2f(((const ushort_t*)b1)[step*ZHD + j]);
      as_[jj] = WS ? wf[OFF_B2 + step*ZHD + j] : bf2f(((const ushort_t*)b2)[step*ZHD + j]);
    }
    #pragma unroll 2
    for (int k=0;k<HSD;++k){
      float hk = hbuf[k*256 + tid];
      if constexpr (WS){
        const float* w1 = wf + OFF_W1T + (step*HSD + k)*ZHD + q*16;
        const float* w2 = wf + OFF_W2T + (step*HSD + k)*ZHD + q*16;
        #pragma unroll
        for (int jj=0;jj<16;++jj){
          am[jj]  = fmaf(hk, w1[jj], am[jj]);
          as_[jj] = fmaf(hk, w2[jj], as_[jj]);
        }
      } else {
        #pragma unroll
        for (int jj=0;jj<16;++jj){
          int j = q*16 + jj;
          am[jj]  = fmaf(hk, bf2f(((const ushort_t*)W1)[(step*ZHD + j)*HSD + k]), am[jj]);
          as_[jj] = fmaf(hk, bf2f(((const ushort_t*)W2)[(step*ZHD + j)*HSD + k]), as_[jj]);
        }
      }
    }
    #pragma unroll
    for (int jj=0;jj<16;++jj){
      int j = q*16 + jj;
      float sig, lsig;
      sigmoid_log(as_[jj], sig, lsig);
      zout[j] = zout[j]*sig + am[jj];
      logdet += lsig;
    }
  }
}

// NOTE: locals are underscore-prefixed so macro args like `ve4.x` can never
// be captured by the declarations inside the macro body (round-2 bug).
#define ZPROC(c, eb, mb, lb) {                         \
    float _ze=(eb), _zm=(mb), _zl=(lb);                \
    slv += _zl; se2 = fmaf(_ze,_ze,se2);               \
    float _zc = fmaf(_ze, __expf(0.5f*_zl), _zm);      \
    if ((c) < ZHD) z1[(c)] = _zc; else z2[(c)-ZHD] = _zc; }

#define ZV(c) ((c) < ZHD ? z1[(c)] : z2[(c)-ZHD])

template<bool WS>
__global__ __launch_bounds__(256, 2) void flow_kernel(
    const void* __restrict__ mean_, const void* __restrict__ logvar_,
    const void* __restrict__ eps_,
    const void* __restrict__ W0, const void* __restrict__ b0,
    const void* __restrict__ W1, const void* __restrict__ b1,
    const void* __restrict__ W2, const void* __restrict__ b2,
    const float* __restrict__ wf,
    void* __restrict__ out_)
{
  __shared__ float hbuf[HSD*256];                 // 50 KB, [k][tid]
  const int tid = threadIdx.x;
  const int r   = blockIdx.x*256 + tid;
  const int b   = r & (BB-1);
  const int flag = detect_bf16((const uint_t*)mean_);

  float z1[ZHD], z2[ZHD];
  float slv = 0.f, se2 = 0.f;

  if (flag){
    const ushort_t* ep = (const ushort_t*)eps_    + (size_t)r*ZSD;
    const ushort_t* mn = (const ushort_t*)mean_   + (size_t)b*ZSD;
    const ushort_t* lv = (const ushort_t*)logvar_ + (size_t)b*ZSD;
    #pragma unroll
    for (int c8=0;c8<ZSD;c8+=8){
      uint4 ue = *(const uint4*)(ep + c8);
      uint4 um = *(const uint4*)(mn + c8);
      uint4 ul = *(const uint4*)(lv + c8);
      ZPROC(c8+0, bflo(ue.x), bflo(um.x), bflo(ul.x));
      ZPROC(c8+1, bfhi(ue.x), bfhi(um.x), bfhi(ul.x));
      ZPROC(c8+2, bflo(ue.y), bflo(um.y), bflo(ul.y));
      ZPROC(c8+3, bfhi(ue.y), bfhi(um.y), bfhi(ul.y));
      ZPROC(c8+4, bflo(ue.z), bflo(um.z), bflo(ul.z));
      ZPROC(c8+5, bfhi(ue.z), bfhi(um.z), bfhi(ul.z));
      ZPROC(c8+6, bflo(ue.w), bflo(um.w), bflo(ul.w));
      ZPROC(c8+7, bfhi(ue.w), bfhi(um.w), bfhi(ul.w));
    }
  } else {
    const float4* ep4 = (const float4*)((const float*)eps_    + (size_t)r*ZSD);
    const float4* mn4 = (const float4*)((const float*)mean_   + (size_t)b*ZSD);
    const float4* lv4 = (const float4*)((const float*)logvar_ + (size_t)b*ZSD);
    #pragma unroll
    for (int c4=0;c4<ZSD/4;++c4){
      float4 ve4 = ep4[c4], vm4 = mn4[c4], vl4 = lv4[c4];
      ZPROC(4*c4+0, ve4.x, vm4.x, vl4.x);
      ZPROC(4*c4+1, ve4.y, vm4.y, vl4.y);
      ZPROC(4*c4+2, ve4.z, vm4.z, vl4.z);
      ZPROC(4*c4+3, ve4.w, vm4.w, vl4.w);
    }
  }

  float logdet = 0.f;
  #pragma unroll 1
  for (int i=0;i<NFD;++i){
    coupling_step<WS>(2*i+0, z1, z2, logdet, wf, W0,b0,W1,b1,W2,b2, hbuf, tid);
    coupling_step<WS>(2*i+1, z2, z1, logdet, wf, W0,b0,W1,b1,W2,b2, hbuf, tid);
  }

  // logqz0 = -0.5*(ZS*ln(2pi) + sum(logvar) + sum(eps^2))
  float logqz0 = -0.5f*((float)ZSD*1.8378770664093453f + slv + se2);
  float logpz  = logqz0 - logdet;

  if (flag){
    ushort_t* oz = (ushort_t*)out_ + (size_t)r*ZSD;
    #pragma unroll
    for (int c8=0;c8<ZSD;c8+=8){
      uint4 o;
      o.x = (uint_t)f2bf(ZV(c8+0)) | ((uint_t)f2bf(ZV(c8+1))<<16);
      o.y = (uint_t)f2bf(ZV(c8+2)) | ((uint_t)f2bf(ZV(c8+3))<<16);
      o.z = (uint_t)f2bf(ZV(c8+4)) | ((uint_t)f2bf(ZV(c8+5))<<16);
      o.w = (uint_t)f2bf(ZV(c8+6)) | ((uint_t)f2bf(ZV(c8+7))<<16);
      *(uint4*)(oz + c8) = o;
    }
    ((ushort_t*)out_)[(size_t)NROWS*ZSD + r] = f2bf(logpz);
  } else {
    float4* oz4 = (float4*)((float*)out_ + (size_t)r*ZSD);
    #pragma unroll
    for (int c4=0;c4<ZSD/4;++c4){
      float4 o;
      o.x = ZV(4*c4+0); o.y = ZV(4*c4+1); o.z = ZV(4*c4+2); o.w = ZV(4*c4+3);
      oz4[c4] = o;
    }
    ((float*)out_)[(size_t)NROWS*ZSD + r] = logpz;
  }
}

extern "C" void kernel_launch(void* const* d_in, const int* in_sizes, int n_in,
                              void* d_out, int out_size, void* d_ws, size_t ws_size,
                              hipStream_t stream)
{
  const void* mean   = d_in[0];
  const void* logvar = d_in[1];
  const void* eps    = d_in[2];
  const void* W0     = d_in[3];
  const void* b0     = d_in[4];
  const void* W1     = d_in[5];
  const void* b1     = d_in[6];
  const void* W2     = d_in[7];
  const void* b2     = d_in[8];

  const bool use_ws = (ws_size >= (size_t)WS_FLOATS*sizeof(float));
  if (use_ws){
    convert_weights<<<(4*HSD*ZHD + 255)/256, 256, 0, stream>>>(W0,b0,W1,b1,W2,b2, mean, (float*)d_ws);
    flow_kernel<true><<<NROWS/256, 256, 0, stream>>>(
        mean,logvar,eps,W0,b0,W1,b1,W2,b2,(const float*)d_ws,d_out);
  } else {
    // no workspace: read weights directly (bf16 assumed in this path)
    flow_kernel<false><<<NROWS/256, 256, 0, stream>>>(
        mean,logvar,eps,W0,b0,W1,b1,W2,b2,(const float*)nullptr,d_out);
  }
}

// Round 4
// 254.037 us; speedup vs baseline: 2.1105x; 2.1105x over previous
//
#include <hip/hip_runtime.h>

// Flow1: RealNVP coupling flow. K=32 B=4096 ZS=128 ZH=64 HS=50 NF=2.
// Round 4: MFMA rewrite. Confirmed fp32 I/O. Per wave: 32 rows (2 M-tiles of
// 16). Each step s (4 total): H = tanh(Zact @ W0p^T + b0p)  [16x16x32 bf16
// MFMA, K=64], then MEW = H @ W1p^T, SIGpre = H @ W2p^T + b2 (K=64, k>=50
// zero-padded), passive z updated in fp32 D-layout registers. Active half and
// H round-trip through per-wave LDS (bf16, A-layout, stride 72 = bank-clean,
// 16B aligned). Weights preconverted to padded bf16 [n][72] in d_ws; staged
// per-step into LDS shared by the block's 4 waves (2 barriers/step).
// logpz via per-quad xor-shuffle reduction.
//
// Layouts (m89/m91-verified, cdna docs):
//   A-frag: A[m][k], m=lane&15, k=quad*8+j (j=0..7) per 32-K-tile
//   B-frag: B[k][n], n=lane&15, k=quad*8+j
//   C/D   : D[m][n], n=lane&15, m=quad*4+reg

typedef unsigned short ushort_t;
typedef unsigned int   uint_t;
typedef short bf8 __attribute__((ext_vector_type(8)));
typedef float f4  __attribute__((ext_vector_type(4)));

#define KK   32
#define BB   4096
#define ZSD  128
#define ZHD  64
#define HSD  50
#define NROWS (KK*BB)

#define WST  72                   // k-stride (shorts) for weight/act tiles
#define MATS (64*WST)             // shorts per padded matrix  = 4608
#define WGL_SHORTS (12*MATS)      // 55296 shorts = 110592 B
#define WS_BYTES   (WGL_SHORTS*2 + 768*4)   // + padded fp32 biases [4][3][64]

__device__ __forceinline__ float bf2f(ushort_t u){ union{uint_t i; float f;} v; v.i = ((uint_t)u)<<16; return v.f; }
__device__ __forceinline__ ushort_t f2bf(float f){
  union{float f; uint_t i;} v; v.f = f;
  uint_t x = v.i;
  return (ushort_t)((x + 0x7fffu + ((x>>16)&1u)) >> 16);   // RNE
}

__device__ __forceinline__ float tanh_fast(float x){
  float ax = fabsf(x);
  float t  = __expf(-2.0f*ax);                  // (0,1]
  float r  = (1.0f - t) / (1.0f + t);
  union{float f; uint_t i;} u, s; u.f = r; s.f = x;
  u.i |= (s.i & 0x80000000u);
  return u.f;
}

__device__ __forceinline__ void sigmoid_log(float x, float& sig, float& lsig){
  float ax  = fabsf(x);
  float e   = __expf(-ax);
  float d   = 1.0f + e;
  float inv = 1.0f / d;
  float ld  = __logf(d);
  bool pos  = (x >= 0.0f);
  sig  = pos ? inv : e*inv;
  lsig = pos ? -ld : x - ld;
}

__device__ __forceinline__ f4 MFMA(bf8 a, bf8 b, f4 c){
  return __builtin_amdgcn_mfma_f32_16x16x32_bf16(a, b, c, 0, 0, 0);
}

// ---- weight preconversion: fp32 -> padded bf16 [step][mat][n][WST] + biases
__global__ void convert_weights(const float* __restrict__ W0g,
                                const float* __restrict__ b0g,
                                const float* __restrict__ W1g,
                                const float* __restrict__ b1g,
                                const float* __restrict__ W2g,
                                const float* __restrict__ b2g,
                                ushort_t* __restrict__ wgl)
{
  int t = blockIdx.x*256 + threadIdx.x;
  if (t < WGL_SHORTS){
    int mi  = t / MATS;             // step*3 + which
    int rem = t % MATS;
    int n   = rem / WST;
    int k   = rem % WST;
    int step  = mi / 3;
    int which = mi % 3;
    float v = 0.0f;
    if (which == 0){                           // B0[k=z][n=h] = W0[step][n][k]
      if (n < HSD && k < ZHD) v = W0g[(step*HSD + n)*ZHD + k];
    } else if (which == 1){                    // B1[k=h][n=z] = W1[step][n][k]
      if (k < HSD)            v = W1g[(step*ZHD + n)*HSD + k];
    } else {
      if (k < HSD)            v = W2g[(step*ZHD + n)*HSD + k];
    }
    wgl[t] = f2bf(v);
  }
  if (t < 768){                                // biases fp32 padded to 64
    float* bp = (float*)(wgl + WGL_SHORTS);
    int step  = t / 192;
    int rem   = t % 192;
    int which = rem / 64;
    int n     = rem % 64;
    float v = 0.0f;
    if (which == 0){ if (n < HSD) v = b0g[step*HSD + n]; }
    else if (which == 1) v = b1g[step*ZHD + n];
    else                 v = b2g[step*ZHD + n];
    bp[t] = v;
  }
}

// one coupling step; pz = passive-half registers (updated), active already in zAw
__device__ __forceinline__ void do_step(
    int s, float (&pz)[2][16], float (&T)[2][4],
    ushort_t* zAw, ushort_t* hAw, ushort_t* wsh,
    const ushort_t* wgl, const float* wsb,
    int quad, int l15, int wr)
{
  // stage this step's 3 matrices into LDS (block-shared)
  __syncthreads();
  {
    const uint4* src = (const uint4*)(wgl + (size_t)s*3*MATS);
    uint4* dst = (uint4*)wsh;
    for (int idx = threadIdx.x; idx < 3*MATS/8; idx += 256) dst[idx] = src[idx];
  }
  __syncthreads();

  // ---- phase A: H = tanh(Zact @ B0 + b0) ----
  bf8 zf[2][2];
  #pragma unroll
  for (int m=0;m<2;++m)
    #pragma unroll
    for (int kt=0;kt<2;++kt)
      zf[m][kt] = *(const bf8*)(zAw + (m*16 + l15)*WST + kt*32 + quad*8);

  #pragma unroll
  for (int nt=0;nt<4;++nt){
    const ushort_t* wb = wsh + (0*64 + nt*16 + l15)*WST + quad*8;
    bf8 w0a = *(const bf8*)(wb);
    bf8 w0b = *(const bf8*)(wb + 32);
    float b0v = wsb[(s*3+0)*64 + nt*16 + l15];
    #pragma unroll
    for (int m=0;m<2;++m){
      f4 acc = {0.f,0.f,0.f,0.f};
      acc = MFMA(zf[m][0], w0a, acc);
      acc = MFMA(zf[m][1], w0b, acc);
      #pragma unroll
      for (int i=0;i<4;++i){
        float h = tanh_fast(acc[i] + b0v);
        hAw[(m*16 + quad*4 + i)*WST + nt*16 + l15] = f2bf(h);
      }
    }
  }

  // ---- phase B: MEW = H@B1 + b1 ; SIG = sigmoid(H@B2 + b2) ----
  bf8 hf[2][2];
  #pragma unroll
  for (int m=0;m<2;++m)
    #pragma unroll
    for (int kt=0;kt<2;++kt)
      hf[m][kt] = *(const bf8*)(hAw + (m*16 + l15)*WST + kt*32 + quad*8);

  #pragma unroll
  for (int nt=0;nt<4;++nt){
    const ushort_t* w1p = wsh + (1*64 + nt*16 + l15)*WST + quad*8;
    const ushort_t* w2p = wsh + (2*64 + nt*16 + l15)*WST + quad*8;
    bf8 w1a = *(const bf8*)(w1p);
    bf8 w1b = *(const bf8*)(w1p + 32);
    bf8 w2a = *(const bf8*)(w2p);
    bf8 w2b = *(const bf8*)(w2p + 32);
    float b1v = wsb[(s*3+1)*64 + nt*16 + l15];
    float b2v = wsb[(s*3+2)*64 + nt*16 + l15];
    #pragma unroll
    for (int m=0;m<2;++m){
      f4 am = {0.f,0.f,0.f,0.f};
      f4 as = {0.f,0.f,0.f,0.f};
      am = MFMA(hf[m][0], w1a, am);
      am = MFMA(hf[m][1], w1b, am);
      as = MFMA(hf[m][0], w2a, as);
      as = MFMA(hf[m][1], w2b, as);
      #pragma unroll
      for (int i=0;i<4;++i){
        float mew  = am[i] + b1v;
        float spre = as[i] + b2v;
        float sig, lsig;
        sigmoid_log(spre, sig, lsig);
        pz[m][nt*4+i] = fmaf(pz[m][nt*4+i], sig, mew);
        T[m][i] += lsig;
      }
    }
  }

  // new active = just-updated passive -> zA (bf16, A-layout)
  if (wr){
    #pragma unroll
    for (int m=0;m<2;++m)
      #pragma unroll
      for (int nt=0;nt<4;++nt)
        #pragma unroll
        for (int i=0;i<4;++i)
          zAw[(m*16 + quad*4 + i)*WST + nt*16 + l15] = f2bf(pz[m][nt*4+i]);
  }
}

__global__ __launch_bounds__(256, 1) void flow_mfma(
    const float* __restrict__ mean, const float* __restrict__ logvar,
    const float* __restrict__ eps,
    const ushort_t* __restrict__ wgl,
    float* __restrict__ out)
{
  __shared__ __align__(16) ushort_t wsh[3*MATS];        // 27648 B
  __shared__ __align__(16) ushort_t zA[4][32*WST];      // 4 x 4608 B
  __shared__ __align__(16) ushort_t hA[4][32*WST];      // 4 x 4608 B

  const int tid  = threadIdx.x;
  const int wave = tid >> 6;
  const int lane = tid & 63;
  const int quad = lane >> 4;
  const int l15  = lane & 15;
  const int rbase = blockIdx.x*128 + wave*32;

  const float* wsb = (const float*)(wgl + WGL_SHORTS);
  ushort_t* zAw = zA[wave];
  ushort_t* hAw = hA[wave];

  // z1D/z2D in C/D layout: [mtile][nt*4+reg] -> row=mtile*16+quad*4+reg,
  // col(z-index within half)=nt*16+l15
  float z1D[2][16], z2D[2][16];
  float T[2][4];                     // T = 0.5*sum(lv+eps^2) + sum(lsig)

  // ---- init: z = eps*exp(0.5*lv)+mean, loaded directly in D-layout ----
  #pragma unroll
  for (int m=0;m<2;++m){
    #pragma unroll
    for (int i=0;i<4;++i){
      int rrow = rbase + m*16 + quad*4 + i;
      int brow = rrow & (BB-1);
      const float* er = eps    + (size_t)rrow*ZSD;
      const float* mr = mean   + (size_t)brow*ZSD;
      const float* vr = logvar + (size_t)brow*ZSD;
      float acc = 0.f;
      #pragma unroll
      for (int nt=0;nt<4;++nt){
        int c1 = nt*16 + l15;
        int c2 = 64 + c1;
        float e1 = er[c1], v1 = vr[c1], m1 = mr[c1];
        float e2 = er[c2], v2 = vr[c2], m2 = mr[c2];
        z1D[m][nt*4+i] = fmaf(e1, __expf(0.5f*v1), m1);
        z2D[m][nt*4+i] = fmaf(e2, __expf(0.5f*v2), m2);
        acc += (v1 + e1*e1) + (v2 + e2*e2);
      }
      T[m][i] = 0.5f*acc;
    }
  }

  // initial active = z1 -> zA
  #pragma unroll
  for (int m=0;m<2;++m)
    #pragma unroll
    for (int nt=0;nt<4;++nt)
      #pragma unroll
      for (int i=0;i<4;++i)
        zAw[(m*16 + quad*4 + i)*WST + nt*16 + l15] = f2bf(z1D[m][nt*4+i]);

  // ---- 4 coupling steps (2 bodies in a non-unrolled loop to bound I$) ----
  #pragma unroll 1
  for (int it=0; it<2; ++it){
    do_step(2*it+0, z2D, T, zAw, hAw, wsh, wgl, wsb, quad, l15, 1);
    do_step(2*it+1, z1D, T, zAw, hAw, wsh, wgl, wsb, quad, l15, it==0);
  }

  // ---- store z_out (fp32) ----
  #pragma unroll
  for (int m=0;m<2;++m){
    #pragma unroll
    for (int i=0;i<4;++i){
      int rrow = rbase + m*16 + quad*4 + i;
      float* orow = out + (size_t)rrow*ZSD;
      #pragma unroll
      for (int nt=0;nt<4;++nt){
        orow[nt*16 + l15]      = z1D[m][nt*4+i];
        orow[64 + nt*16 + l15] = z2D[m][nt*4+i];
      }
    }
  }

  // ---- logpz = -0.5*128*ln(2pi) - T_rowsum ; reduce T across the 16 lanes
  // of each quad (they cover all 128 cols of rows quad*4+reg) ----
  #pragma unroll
  for (int m=0;m<2;++m)
    #pragma unroll
    for (int i=0;i<4;++i){
      float v = T[m][i];
      v += __shfl_xor(v, 1, 64);
      v += __shfl_xor(v, 2, 64);
      v += __shfl_xor(v, 4, 64);
      v += __shfl_xor(v, 8, 64);
      T[m][i] = v;
    }
  if (l15 == 0){
    const float NC = -0.5f * 128.0f * 1.8378770664093453f;
    #pragma unroll
    for (int m=0;m<2;++m)
      #pragma unroll
      for (int i=0;i<4;++i){
        int rrow = rbase + m*16 + quad*4 + i;
        out[(size_t)NROWS*ZSD + rrow] = NC - T[m][i];
      }
  }
}

extern "C" void kernel_launch(void* const* d_in, const int* in_sizes, int n_in,
                              void* d_out, int out_size, void* d_ws, size_t ws_size,
                              hipStream_t stream)
{
  const float* mean   = (const float*)d_in[0];
  const float* logvar = (const float*)d_in[1];
  const float* eps    = (const float*)d_in[2];
  const float* W0     = (const float*)d_in[3];
  const float* b0     = (const float*)d_in[4];
  const float* W1     = (const float*)d_in[5];
  const float* b1     = (const float*)d_in[6];
  const float* W2     = (const float*)d_in[7];
  const float* b2     = (const float*)d_in[8];
  ushort_t* wgl = (ushort_t*)d_ws;          // ws_size >= 156448 proven round 3

  convert_weights<<<(WGL_SHORTS + 255)/256, 256, 0, stream>>>(W0,b0,W1,b1,W2,b2, wgl);
  flow_mfma<<<NROWS/128, 256, 0, stream>>>(mean, logvar, eps, wgl, (float*)d_out);
}